// Round 9
// baseline (102955.811 us; speedup 1.0000x reference)
//
#include <hip/hip_runtime.h>
#include <math.h>

// GRU RNN: T=32768, 2 layers H=512, in=128, out=128, fp32.
// v9 = v8 (PASSED 66.3ms; fused 2-layer pipelined 48-block persistent scan)
//      + pipelined-snapshot polls.
// v8 post-mortem: nchunk=2, C=16384 -> real step = 2.0us. Interleaving the
// two polls changed nothing -> the binding term is poll RETRY QUANTIZATION:
// first poll after publish misses (data not yet through the coherence
// point), retry period = 1 fabric RT, overshoot ~1-1.5 RT, tail-amplified
// by the max-over-48-blocks coupling of the all-to-all exchange.
// Fix: each poll keeps 3 loads outstanding to the same address, checked
// oldest-first (compiler emits counted vmcnt waits), reissued when stale ->
// flag snapshots every ~RT/3 instead of every RT; detection mean AND
// variance drop. Tag-validated snapshots, monotone visibility -> identical
// values written; no new dataflow vs v8.
// Structure:
//   L1: 16 blocks x 32 rows, k=512; L2: 32 blocks x 16 rows, k=1024 (concat
//   [h1[t] || h2[t-1]]; folds the former igates1 GEMM into the scan).
//   ring1 full-chunk tagged (no wraparound); ring2 depth-4 tagged.
//   Per chunk: ig0 GEMM -> fused scan -> out GEMM.

#define TSTEPS 32768
#define HDIM   512
#define G3     1536
#define NB1    16          // layer-1 blocks
#define NB2    32          // layer-2 blocks
#define S1     32          // rows per L1 block
#define S2     16          // rows per L2 block
#define RING2  4

#define AL(P) __hip_atomic_load((P), __ATOMIC_RELAXED, __HIP_MEMORY_SCOPE_AGENT)

// Call-free gate functions (saturation-safe at +/-inf, no NaN):
__device__ __forceinline__ float sigf(float x) {
  return 1.f / (1.f + __expf(-x));
}
__device__ __forceinline__ float tanhfast(float x) {
  const float E = __expf(2.f * x);        // inf -> 1-0=1 ; 0 -> 1-2=-1
  return 1.f - 2.f / (E + 1.f);
}
// Pin a float4 in VGPRs (kept from v5 baseline; harmless).
__device__ __forceinline__ void pin4(float4& v) {
  asm volatile("" : "+v"(v.x), "+v"(v.y), "+v"(v.z), "+v"(v.w));
}

// ---------------------------------------------------------------------------
// GEMM: C[M,N] = A[M,K] * B[N,K]^T + bias[N].  BM=128 BN=64 BK=16, 256 thr.
// ---------------------------------------------------------------------------
template<int K>
__global__ __launch_bounds__(256)
void gemm_tn(const float* __restrict__ A, const float* __restrict__ B,
             const float* __restrict__ bias, float* __restrict__ C, int N) {
  __shared__ float As[16][128];
  __shared__ float Bs[16][64];
  const int bm  = blockIdx.x * 128;
  const int bn  = blockIdx.y * 64;
  const int tid = threadIdx.x;
  const int tx  = tid & 15;
  const int ty  = tid >> 4;
  const int lr  = tid >> 2;
  const int lk  = tid & 3;

  float acc[8][4];
#pragma unroll
  for (int i = 0; i < 8; ++i)
#pragma unroll
    for (int jj = 0; jj < 4; ++jj) acc[i][jj] = 0.f;

  for (int k0 = 0; k0 < K; k0 += 16) {
    float4 a0 = *(const float4*)&A[(size_t)(bm + lr) * K + k0 + lk * 4];
    float4 a1 = *(const float4*)&A[(size_t)(bm + lr + 64) * K + k0 + lk * 4];
    float4 bb = *(const float4*)&B[(size_t)(bn + lr) * K + k0 + lk * 4];
    __syncthreads();
    As[lk*4+0][lr]    = a0.x; As[lk*4+1][lr]    = a0.y;
    As[lk*4+2][lr]    = a0.z; As[lk*4+3][lr]    = a0.w;
    As[lk*4+0][lr+64] = a1.x; As[lk*4+1][lr+64] = a1.y;
    As[lk*4+2][lr+64] = a1.z; As[lk*4+3][lr+64] = a1.w;
    Bs[lk*4+0][lr] = bb.x; Bs[lk*4+1][lr] = bb.y;
    Bs[lk*4+2][lr] = bb.z; Bs[lk*4+3][lr] = bb.w;
    __syncthreads();
#pragma unroll
    for (int kk = 0; kk < 16; ++kk) {
      float4 b4  = *(const float4*)&Bs[kk][tx*4];
      float4 av0 = *(const float4*)&As[kk][ty*8];
      float4 av1 = *(const float4*)&As[kk][ty*8+4];
      float av[8] = {av0.x,av0.y,av0.z,av0.w,av1.x,av1.y,av1.z,av1.w};
#pragma unroll
      for (int i = 0; i < 8; ++i) {
        acc[i][0] += av[i]*b4.x; acc[i][1] += av[i]*b4.y;
        acc[i][2] += av[i]*b4.z; acc[i][3] += av[i]*b4.w;
      }
    }
  }
  float4 bv = *(const float4*)&bias[bn + tx*4];
#pragma unroll
  for (int i = 0; i < 8; ++i) {
    float4 o;
    o.x = acc[i][0] + bv.x; o.y = acc[i][1] + bv.y;
    o.z = acc[i][2] + bv.z; o.w = acc[i][3] + bv.w;
    *(float4*)&C[(size_t)(bm + ty*8 + i) * N + bn + tx*4] = o;
  }
}

// ---------------------------------------------------------------------------
// Fused 2-layer pipelined scan. Grid = NB1 + NB2 = 48 blocks x 512 threads.
// ---------------------------------------------------------------------------
__global__ __launch_bounds__(512, 2)
void gru2_scan(const float* __restrict__ ig0,   // [C][1536] layer-1 igates
               const float* __restrict__ Whh0,  // [1536][512]
               const float* __restrict__ bn0,   // [512]
               const float* __restrict__ Wih1,  // [1536][512]
               const float* __restrict__ Whh1,  // [1536][512]
               const float* __restrict__ b1v,   // [1536]
               const float* __restrict__ bn1,   // [512]
               float* __restrict__ h1carry,     // [512] cross-chunk carry
               float* __restrict__ h2c,         // [C][512] layer-2 history
               unsigned long long* __restrict__ ring1, // [C][512]
               unsigned long long* __restrict__ ring2, // [RING2][512]
               int C, unsigned t0, int first)
{
  const int tid = threadIdx.x;
  __shared__ __align__(16) float u[2][1024];   // L1 uses [.][0..511]
  __shared__ float igl[2][96];

  if (blockIdx.x < NB1) {
    // =================== layer 1 ===================
    const int b  = blockIdx.x;
    const int j  = tid >> 4;        // 0..31 row in slice
    const int g  = tid & 15;        // k-group (32 floats)
    const int jg = b * S1 + j;
    float4 wr[8], wz[8], wn[8];
    {
      const float* Wr = Whh0 + (size_t)jg            * HDIM + g * 32;
      const float* Wz = Whh0 + (size_t)(HDIM  + jg)  * HDIM + g * 32;
      const float* Wn = Whh0 + (size_t)(2*HDIM + jg) * HDIM + g * 32;
#pragma unroll
      for (int i = 0; i < 8; ++i) {
        const int c = (i + g) & 7;            // rotation: 2-way banks (free)
        wr[i] = *(const float4*)(Wr + c * 4);
        wz[i] = *(const float4*)(Wz + c * 4);
        wn[i] = *(const float4*)(Wn + c * 4);
      }
    }
#pragma unroll
    for (int i = 0; i < 8; ++i) { pin4(wr[i]); pin4(wz[i]); pin4(wn[i]); }
    const float bnj = bn0[jg];
    u[0][tid] = first ? 0.f : h1carry[tid];
    if (tid < 96)
      igl[0][tid] = ig0[(size_t)(tid >> 5) * HDIM + b * S1 + (tid & 31)];
    const int pm = (tid < b * S1) ? tid : tid + S1;   // 480 pollers
    __syncthreads();

    int p = 0;
    for (int t = 0; t < C; ++t) {
      float pfn = 0.f;
      if (tid < 96 && t + 1 < C)
        pfn = ig0[(size_t)(t + 1) * G3 + (size_t)(tid >> 5) * HDIM
                  + b * S1 + (tid & 31)];

      const float4* h4 = (const float4*)u[p];
      float4 ar = make_float4(0,0,0,0), az = make_float4(0,0,0,0),
             an = make_float4(0,0,0,0);
#pragma unroll
      for (int i = 0; i < 8; ++i) {
        const int c = (i + g) & 7;
        const float4 hv = h4[g * 8 + c];
        ar.x += wr[i].x*hv.x; ar.y += wr[i].y*hv.y; ar.z += wr[i].z*hv.z; ar.w += wr[i].w*hv.w;
        az.x += wz[i].x*hv.x; az.y += wz[i].y*hv.y; az.z += wz[i].z*hv.z; az.w += wz[i].w*hv.w;
        an.x += wn[i].x*hv.x; an.y += wn[i].y*hv.y; an.z += wn[i].z*hv.z; an.w += wn[i].w*hv.w;
      }
      float sr = (ar.x + ar.y) + (ar.z + ar.w);
      float sz = (az.x + az.y) + (az.z + az.w);
      float sn = (an.x + an.y) + (an.z + an.w);
      sr += __shfl_xor(sr,1); sr += __shfl_xor(sr,2); sr += __shfl_xor(sr,4); sr += __shfl_xor(sr,8);
      sz += __shfl_xor(sz,1); sz += __shfl_xor(sz,2); sz += __shfl_xor(sz,4); sz += __shfl_xor(sz,8);
      sn += __shfl_xor(sn,1); sn += __shfl_xor(sn,2); sn += __shfl_xor(sn,4); sn += __shfl_xor(sn,8);

      const unsigned tag = t0 + (unsigned)t + 1u;
      if (g == 0) {
        const float* igc = igl[t & 1];
        const float r = sigf(igc[j]      + sr);
        const float z = sigf(igc[32 + j] + sz);
        const float n = tanhfast(igc[64 + j] + r * (sn + bnj));
        const float hnew = n + z * (u[p][jg] - n);
        __hip_atomic_store(&ring1[(size_t)t * HDIM + jg],
            ((unsigned long long)tag << 32) | (unsigned)__float_as_uint(hnew),
            __ATOMIC_RELAXED, __HIP_MEMORY_SCOPE_AGENT);
        u[p ^ 1][jg] = hnew;
        if (t == C - 1) h1carry[jg] = hnew;
      }
      if (tid < 96 && t + 1 < C) igl[(t + 1) & 1][tid] = pfn;

      if (tid < HDIM - S1) {          // peers' h1[t]: 3-deep snapshot pipe
        const unsigned long long* ap = &ring1[(size_t)t * HDIM + pm];
        unsigned long long s0 = AL(ap), s1 = AL(ap), s2 = AL(ap);
        float hv;
        for (;;) {
          if ((unsigned)(s0 >> 32) == tag) { hv = __uint_as_float((unsigned)s0); break; }
          s0 = AL(ap);
          if ((unsigned)(s1 >> 32) == tag) { hv = __uint_as_float((unsigned)s1); break; }
          s1 = AL(ap);
          if ((unsigned)(s2 >> 32) == tag) { hv = __uint_as_float((unsigned)s2); break; }
          s2 = AL(ap);
        }
        u[p ^ 1][pm] = hv;
      }
      __syncthreads();
      p ^= 1;
    }
  } else {
    // =================== layer 2 ===================
    const int b  = blockIdx.x - NB1;
    const int j  = tid >> 5;        // 0..15 row in slice
    const int g  = tid & 31;        // k-group (32 of 1024 floats)
    const int jg = b * S2 + j;
    float4 wr[8], wz[8], wn[8];
    {
      const float* base = (g < 16) ? Wih1 : Whh1;   // concat [h1 || h2] k-split
      const int gk = (g & 15) * 32;
      const float* Wr = base + (size_t)jg            * HDIM + gk;
      const float* Wz = base + (size_t)(HDIM  + jg)  * HDIM + gk;
      const float* Wn = base + (size_t)(2*HDIM + jg) * HDIM + gk;
#pragma unroll
      for (int i = 0; i < 8; ++i) {
        const int c = (i + g) & 7;
        wr[i] = *(const float4*)(Wr + c * 4);
        wz[i] = *(const float4*)(Wz + c * 4);
        wn[i] = *(const float4*)(Wn + c * 4);
      }
    }
#pragma unroll
    for (int i = 0; i < 8; ++i) { pin4(wr[i]); pin4(wz[i]); pin4(wn[i]); }
    const float b1r = b1v[jg], b1z = b1v[HDIM + jg], b1n = b1v[2*HDIM + jg];
    const float bnj = bn1[jg];

    // init: u[0] = [h1[0] (poll) || h2 carry]   (exactly v8)
    u[0][512 + tid] = first ? 0.f : h2c[(size_t)(C - 1) * HDIM + tid];
    {
      unsigned long long vv;
      do {
        vv = AL(&ring1[tid]);
      } while ((unsigned)(vv >> 32) != t0 + 1u);
      u[0][tid] = __uint_as_float((unsigned)vv);
    }
    const int pm2 = (tid < b * S2) ? tid : tid + S2;  // 496 pollers
    __syncthreads();

    int p = 0;
    for (int t = 0; t < C; ++t) {
      const float4* u4 = (const float4*)u[p];
      float4 ar = make_float4(0,0,0,0), az = make_float4(0,0,0,0),
             an = make_float4(0,0,0,0);
#pragma unroll
      for (int i = 0; i < 8; ++i) {
        const int c = (i + g) & 7;
        const float4 hv = u4[g * 8 + c];
        ar.x += wr[i].x*hv.x; ar.y += wr[i].y*hv.y; ar.z += wr[i].z*hv.z; ar.w += wr[i].w*hv.w;
        az.x += wz[i].x*hv.x; az.y += wz[i].y*hv.y; az.z += wz[i].z*hv.z; az.w += wz[i].w*hv.w;
        an.x += wn[i].x*hv.x; an.y += wn[i].y*hv.y; an.z += wn[i].z*hv.z; an.w += wn[i].w*hv.w;
      }
      float sr = (ar.x + ar.y) + (ar.z + ar.w);
      float sz = (az.x + az.y) + (az.z + az.w);
      float sn = (an.x + an.y) + (an.z + an.w);
      // r,z: full 32-lane sum. n: keep ih half (g<16) and hh half separate.
      sr += __shfl_xor(sr,1); sr += __shfl_xor(sr,2); sr += __shfl_xor(sr,4); sr += __shfl_xor(sr,8);
      sz += __shfl_xor(sz,1); sz += __shfl_xor(sz,2); sz += __shfl_xor(sz,4); sz += __shfl_xor(sz,8);
      sn += __shfl_xor(sn,1); sn += __shfl_xor(sn,2); sn += __shfl_xor(sn,4); sn += __shfl_xor(sn,8);
      sr += __shfl_xor(sr, 16);
      sz += __shfl_xor(sz, 16);
      const float snb = __shfl_xor(sn, 16);   // at g==0: hh-half sum

      const unsigned tag = t0 + (unsigned)t + 1u;
      if (g == 0) {
        const float r = sigf(sr + b1r);
        const float z = sigf(sz + b1z);
        const float n = tanhfast((sn + b1n) + r * (snb + bnj));
        const float hnew = n + z * (u[p][512 + jg] - n);
        h2c[(size_t)t * HDIM + jg] = hnew;
        __hip_atomic_store(&ring2[(size_t)((t & (RING2-1)) << 9) + jg],
            ((unsigned long long)tag << 32) | (unsigned)__float_as_uint(hnew),
            __ATOMIC_RELAXED, __HIP_MEMORY_SCOPE_AGENT);
        u[p ^ 1][512 + jg] = hnew;
      }

      // v8's combined poll (h1[t+1] -> u[p^1][tid]; peers' h2[t] ->
      // u[p^1][512+pm2]), now with 3 outstanding snapshots per address,
      // checked oldest-first and reissued when stale.
      {
        bool n1 = (t + 1 < C);
        bool n2 = (tid < HDIM - S2);
        const unsigned long long* p1 = &ring1[(size_t)(t + 1) * HDIM + tid];
        const unsigned long long* q2 = &ring2[(size_t)((t & (RING2-1)) << 9) + pm2];
        const unsigned w1 = tag + 1u, w2 = tag;
        unsigned long long a0=0, a1=0, a2=0, c0=0, c1=0, c2=0;
        if (n1) { a0 = AL(p1); a1 = AL(p1); a2 = AL(p1); }
        if (n2) { c0 = AL(q2); c1 = AL(q2); c2 = AL(q2); }
        while (n1 || n2) {
          if (n1) {
            if ((unsigned)(a0 >> 32) == w1) { u[p^1][tid] = __uint_as_float((unsigned)a0); n1 = false; }
            else a0 = AL(p1);
          }
          if (n2) {
            if ((unsigned)(c0 >> 32) == w2) { u[p^1][512+pm2] = __uint_as_float((unsigned)c0); n2 = false; }
            else c0 = AL(q2);
          }
          if (n1) {
            if ((unsigned)(a1 >> 32) == w1) { u[p^1][tid] = __uint_as_float((unsigned)a1); n1 = false; }
            else a1 = AL(p1);
          }
          if (n2) {
            if ((unsigned)(c1 >> 32) == w2) { u[p^1][512+pm2] = __uint_as_float((unsigned)c1); n2 = false; }
            else c1 = AL(q2);
          }
          if (n1) {
            if ((unsigned)(a2 >> 32) == w1) { u[p^1][tid] = __uint_as_float((unsigned)a2); n1 = false; }
            else a2 = AL(p1);
          }
          if (n2) {
            if ((unsigned)(c2 >> 32) == w2) { u[p^1][512+pm2] = __uint_as_float((unsigned)c2); n2 = false; }
            else c2 = AL(q2);
          }
        }
      }
      __syncthreads();
      p ^= 1;
    }
  }
}

// ---------------------------------------------------------------------------
extern "C" void kernel_launch(void* const* d_in, const int* in_sizes, int n_in,
                              void* d_out, int out_size, void* d_ws, size_t ws_size,
                              hipStream_t stream) {
  const float* xs    = (const float*)d_in[0];
  const float* W_ih0 = (const float*)d_in[1];
  const float* W_hh0 = (const float*)d_in[2];
  const float* b0    = (const float*)d_in[3];
  const float* bn0   = (const float*)d_in[4];
  const float* W_ih1 = (const float*)d_in[5];
  const float* W_hh1 = (const float*)d_in[6];
  const float* b1    = (const float*)d_in[7];
  const float* bn1   = (const float*)d_in[8];
  const float* W_lin = (const float*)d_in[9];
  const float* b_lin = (const float*)d_in[10];
  float* out = (float*)d_out;

  // ws layout per chunk of C steps:
  //   ig0[C*1536] f32 | h2c[C*512] f32 | ring1[C*512] u64 | ring2[4*512] u64
  //   | h1carry[512] f32
  const size_t TAIL = (size_t)RING2 * HDIM * 8 + HDIM * 4;   // 18 KB
  int C = TSTEPS;
  while (C > 256 && (size_t)C * 12288 + TAIL > ws_size) C >>= 1;
  if ((size_t)C * 12288 + TAIL > ws_size) return;

  char* ws = (char*)d_ws;
  float*              igb = (float*)(ws);
  float*              h2c = (float*)(ws + (size_t)C * 6144);
  unsigned long long* r1  = (unsigned long long*)(ws + (size_t)C * 8192);
  unsigned long long* r2  = (unsigned long long*)(ws + (size_t)C * 12288);
  float*              h1c = (float*)(ws + (size_t)C * 12288 + RING2 * HDIM * 8);

  // Insurance: tags must start != any t0+t+1 (0xAA poison already can't match).
  hipMemsetAsync(r1, 0, (size_t)C * HDIM * 8 + RING2 * HDIM * 8, stream);

  const int nchunk = TSTEPS / C;
  for (int c = 0; c < nchunk; ++c) {
    const size_t t0 = (size_t)c * C;
    const int first = (c == 0);
    // igates0 = xs[t0:t0+C] @ W_ih0^T + b0     [C x 1536], K=128
    gemm_tn<128><<<dim3(C/128, G3/64), 256, 0, stream>>>(
        xs + t0 * 128, W_ih0, b0, igb, G3);
    // fused pipelined 2-layer scan chunk -> h2c
    gru2_scan<<<NB1 + NB2, 512, 0, stream>>>(
        igb, W_hh0, bn0, W_ih1, W_hh1, b1, bn1, h1c, h2c,
        r1, r2, C, (unsigned)t0, first);
    // out chunk = h2c @ W_lin^T + b_lin        [C x 128], K=512
    gemm_tn<512><<<dim3(C/128, 128/64), 256, 0, stream>>>(
        h2c, W_lin, b_lin, out + t0 * 128, 128);
  }
}

// Round 11
// 66441.309 us; speedup vs baseline: 1.5496x; 1.5496x over previous
//
#include <hip/hip_runtime.h>
#include <math.h>

// GRU RNN: T=32768, 2 layers H=512, in=128, out=128, fp32.
// v10 = v8 (PASSED 66.3ms; fused 2-layer pipelined 48-block persistent scan,
//       interleaved polls) with ONE change: __launch_bounds__(512, 1).
// (Round 10 resubmission: round-10 bench was a GPU-acquisition timeout; v10
//  never measured. No changes vs the round-9 submission.)
// v9 post-mortem: 3-deep snapshot polls REGRESSED (scan 32->80ms; FETCH 1.27GB,
// VALUBusy 6.4->4.2% = more vmcnt stall + coherence-point queueing). Reverted.
// v10 theory: VGPR_Count=80 in ALL variants while each thread needs 96 weight
// floats live -> weights re-streamed from L2 every step (~500-900cy of the
// ~4700cy step). Cause: __launch_bounds__(512,2) caps the allocator at ~128
// VGPRs (2 blocks/CU target); 96 weights + ~50 working set busts it, so the
// allocator spills weights (and v5's pin4 was moot: pressure > budget).
// With only 48 blocks on 256 CUs, occupancy >1 block/CU is worthless ->
// lift the cap: min-waves=1 gives the full 256-VGPR budget.
// Structure:
//   L1: 16 blocks x 32 rows, k=512; L2: 32 blocks x 16 rows, k=1024 (concat
//   [h1[t] || h2[t-1]]; folds the former igates1 GEMM into the scan).
//   ring1 full-chunk tagged (no wraparound); ring2 depth-4 tagged.
//   Per chunk: ig0 GEMM -> fused scan -> out GEMM.

#define TSTEPS 32768
#define HDIM   512
#define G3     1536
#define NB1    16          // layer-1 blocks
#define NB2    32          // layer-2 blocks
#define S1     32          // rows per L1 block
#define S2     16          // rows per L2 block
#define RING2  4

#define AL(P) __hip_atomic_load((P), __ATOMIC_RELAXED, __HIP_MEMORY_SCOPE_AGENT)

// Call-free gate functions (saturation-safe at +/-inf, no NaN):
__device__ __forceinline__ float sigf(float x) {
  return 1.f / (1.f + __expf(-x));
}
__device__ __forceinline__ float tanhfast(float x) {
  const float E = __expf(2.f * x);        // inf -> 1-0=1 ; 0 -> 1-2=-1
  return 1.f - 2.f / (E + 1.f);
}
// Pin a float4 in VGPRs (no-op anchor; effective only now that the
// register budget allows residency).
__device__ __forceinline__ void pin4(float4& v) {
  asm volatile("" : "+v"(v.x), "+v"(v.y), "+v"(v.z), "+v"(v.w));
}

// ---------------------------------------------------------------------------
// GEMM: C[M,N] = A[M,K] * B[N,K]^T + bias[N].  BM=128 BN=64 BK=16, 256 thr.
// ---------------------------------------------------------------------------
template<int K>
__global__ __launch_bounds__(256)
void gemm_tn(const float* __restrict__ A, const float* __restrict__ B,
             const float* __restrict__ bias, float* __restrict__ C, int N) {
  __shared__ float As[16][128];
  __shared__ float Bs[16][64];
  const int bm  = blockIdx.x * 128;
  const int bn  = blockIdx.y * 64;
  const int tid = threadIdx.x;
  const int tx  = tid & 15;
  const int ty  = tid >> 4;
  const int lr  = tid >> 2;
  const int lk  = tid & 3;

  float acc[8][4];
#pragma unroll
  for (int i = 0; i < 8; ++i)
#pragma unroll
    for (int jj = 0; jj < 4; ++jj) acc[i][jj] = 0.f;

  for (int k0 = 0; k0 < K; k0 += 16) {
    float4 a0 = *(const float4*)&A[(size_t)(bm + lr) * K + k0 + lk * 4];
    float4 a1 = *(const float4*)&A[(size_t)(bm + lr + 64) * K + k0 + lk * 4];
    float4 bb = *(const float4*)&B[(size_t)(bn + lr) * K + k0 + lk * 4];
    __syncthreads();
    As[lk*4+0][lr]    = a0.x; As[lk*4+1][lr]    = a0.y;
    As[lk*4+2][lr]    = a0.z; As[lk*4+3][lr]    = a0.w;
    As[lk*4+0][lr+64] = a1.x; As[lk*4+1][lr+64] = a1.y;
    As[lk*4+2][lr+64] = a1.z; As[lk*4+3][lr+64] = a1.w;
    Bs[lk*4+0][lr] = bb.x; Bs[lk*4+1][lr] = bb.y;
    Bs[lk*4+2][lr] = bb.z; Bs[lk*4+3][lr] = bb.w;
    __syncthreads();
#pragma unroll
    for (int kk = 0; kk < 16; ++kk) {
      float4 b4  = *(const float4*)&Bs[kk][tx*4];
      float4 av0 = *(const float4*)&As[kk][ty*8];
      float4 av1 = *(const float4*)&As[kk][ty*8+4];
      float av[8] = {av0.x,av0.y,av0.z,av0.w,av1.x,av1.y,av1.z,av1.w};
#pragma unroll
      for (int i = 0; i < 8; ++i) {
        acc[i][0] += av[i]*b4.x; acc[i][1] += av[i]*b4.y;
        acc[i][2] += av[i]*b4.z; acc[i][3] += av[i]*b4.w;
      }
    }
  }
  float4 bv = *(const float4*)&bias[bn + tx*4];
#pragma unroll
  for (int i = 0; i < 8; ++i) {
    float4 o;
    o.x = acc[i][0] + bv.x; o.y = acc[i][1] + bv.y;
    o.z = acc[i][2] + bv.z; o.w = acc[i][3] + bv.w;
    *(float4*)&C[(size_t)(bm + ty*8 + i) * N + bn + tx*4] = o;
  }
}

// ---------------------------------------------------------------------------
// Fused 2-layer pipelined scan. Grid = NB1 + NB2 = 48 blocks x 512 threads.
// __launch_bounds__(512, 1): full 256-VGPR budget so the 96 weight floats
// per thread stay register-resident (48 blocks on 256 CUs -> occupancy >1
// block/CU is worthless).
// ---------------------------------------------------------------------------
__global__ __launch_bounds__(512, 1)
void gru2_scan(const float* __restrict__ ig0,   // [C][1536] layer-1 igates
               const float* __restrict__ Whh0,  // [1536][512]
               const float* __restrict__ bn0,   // [512]
               const float* __restrict__ Wih1,  // [1536][512]
               const float* __restrict__ Whh1,  // [1536][512]
               const float* __restrict__ b1v,   // [1536]
               const float* __restrict__ bn1,   // [512]
               float* __restrict__ h1carry,     // [512] cross-chunk carry
               float* __restrict__ h2c,         // [C][512] layer-2 history
               unsigned long long* __restrict__ ring1, // [C][512]
               unsigned long long* __restrict__ ring2, // [RING2][512]
               int C, unsigned t0, int first)
{
  const int tid = threadIdx.x;
  __shared__ __align__(16) float u[2][1024];   // L1 uses [.][0..511]
  __shared__ float igl[2][96];

  if (blockIdx.x < NB1) {
    // =================== layer 1 (identical to v8) ===================
    const int b  = blockIdx.x;
    const int j  = tid >> 4;        // 0..31 row in slice
    const int g  = tid & 15;        // k-group (32 floats)
    const int jg = b * S1 + j;
    float4 wr[8], wz[8], wn[8];
    {
      const float* Wr = Whh0 + (size_t)jg            * HDIM + g * 32;
      const float* Wz = Whh0 + (size_t)(HDIM  + jg)  * HDIM + g * 32;
      const float* Wn = Whh0 + (size_t)(2*HDIM + jg) * HDIM + g * 32;
#pragma unroll
      for (int i = 0; i < 8; ++i) {
        const int c = (i + g) & 7;            // rotation: 2-way banks (free)
        wr[i] = *(const float4*)(Wr + c * 4);
        wz[i] = *(const float4*)(Wz + c * 4);
        wn[i] = *(const float4*)(Wn + c * 4);
      }
    }
#pragma unroll
    for (int i = 0; i < 8; ++i) { pin4(wr[i]); pin4(wz[i]); pin4(wn[i]); }
    const float bnj = bn0[jg];
    u[0][tid] = first ? 0.f : h1carry[tid];
    if (tid < 96)
      igl[0][tid] = ig0[(size_t)(tid >> 5) * HDIM + b * S1 + (tid & 31)];
    const int pm = (tid < b * S1) ? tid : tid + S1;   // 480 pollers
    __syncthreads();

    int p = 0;
    for (int t = 0; t < C; ++t) {
      float pfn = 0.f;
      if (tid < 96 && t + 1 < C)
        pfn = ig0[(size_t)(t + 1) * G3 + (size_t)(tid >> 5) * HDIM
                  + b * S1 + (tid & 31)];

      const float4* h4 = (const float4*)u[p];
      float4 ar = make_float4(0,0,0,0), az = make_float4(0,0,0,0),
             an = make_float4(0,0,0,0);
#pragma unroll
      for (int i = 0; i < 8; ++i) {
        const int c = (i + g) & 7;
        const float4 hv = h4[g * 8 + c];
        ar.x += wr[i].x*hv.x; ar.y += wr[i].y*hv.y; ar.z += wr[i].z*hv.z; ar.w += wr[i].w*hv.w;
        az.x += wz[i].x*hv.x; az.y += wz[i].y*hv.y; az.z += wz[i].z*hv.z; az.w += wz[i].w*hv.w;
        an.x += wn[i].x*hv.x; an.y += wn[i].y*hv.y; an.z += wn[i].z*hv.z; an.w += wn[i].w*hv.w;
      }
      float sr = (ar.x + ar.y) + (ar.z + ar.w);
      float sz = (az.x + az.y) + (az.z + az.w);
      float sn = (an.x + an.y) + (an.z + an.w);
      sr += __shfl_xor(sr,1); sr += __shfl_xor(sr,2); sr += __shfl_xor(sr,4); sr += __shfl_xor(sr,8);
      sz += __shfl_xor(sz,1); sz += __shfl_xor(sz,2); sz += __shfl_xor(sz,4); sz += __shfl_xor(sz,8);
      sn += __shfl_xor(sn,1); sn += __shfl_xor(sn,2); sn += __shfl_xor(sn,4); sn += __shfl_xor(sn,8);

      const unsigned tag = t0 + (unsigned)t + 1u;
      if (g == 0) {
        const float* igc = igl[t & 1];
        const float r = sigf(igc[j]      + sr);
        const float z = sigf(igc[32 + j] + sz);
        const float n = tanhfast(igc[64 + j] + r * (sn + bnj));
        const float hnew = n + z * (u[p][jg] - n);
        __hip_atomic_store(&ring1[(size_t)t * HDIM + jg],
            ((unsigned long long)tag << 32) | (unsigned)__float_as_uint(hnew),
            __ATOMIC_RELAXED, __HIP_MEMORY_SCOPE_AGENT);
        u[p ^ 1][jg] = hnew;
        if (t == C - 1) h1carry[jg] = hnew;
      }
      if (tid < 96 && t + 1 < C) igl[(t + 1) & 1][tid] = pfn;

      if (tid < HDIM - S1) {                    // gather peers' h1[t]
        unsigned long long vv;
        do {
          vv = AL(&ring1[(size_t)t * HDIM + pm]);
        } while ((unsigned)(vv >> 32) != tag);
        u[p ^ 1][pm] = __uint_as_float((unsigned)vv);
      }
      __syncthreads();
      p ^= 1;
    }
  } else {
    // =================== layer 2 (identical to v8) ===================
    const int b  = blockIdx.x - NB1;
    const int j  = tid >> 5;        // 0..15 row in slice
    const int g  = tid & 31;        // k-group (32 of 1024 floats)
    const int jg = b * S2 + j;
    float4 wr[8], wz[8], wn[8];
    {
      const float* base = (g < 16) ? Wih1 : Whh1;   // concat [h1 || h2] k-split
      const int gk = (g & 15) * 32;
      const float* Wr = base + (size_t)jg            * HDIM + gk;
      const float* Wz = base + (size_t)(HDIM  + jg)  * HDIM + gk;
      const float* Wn = base + (size_t)(2*HDIM + jg) * HDIM + gk;
#pragma unroll
      for (int i = 0; i < 8; ++i) {
        const int c = (i + g) & 7;
        wr[i] = *(const float4*)(Wr + c * 4);
        wz[i] = *(const float4*)(Wz + c * 4);
        wn[i] = *(const float4*)(Wn + c * 4);
      }
    }
#pragma unroll
    for (int i = 0; i < 8; ++i) { pin4(wr[i]); pin4(wz[i]); pin4(wn[i]); }
    const float b1r = b1v[jg], b1z = b1v[HDIM + jg], b1n = b1v[2*HDIM + jg];
    const float bnj = bn1[jg];

    // init: u[0] = [h1[0] (poll) || h2 carry]
    u[0][512 + tid] = first ? 0.f : h2c[(size_t)(C - 1) * HDIM + tid];
    {
      unsigned long long vv;
      do {
        vv = AL(&ring1[tid]);
      } while ((unsigned)(vv >> 32) != t0 + 1u);
      u[0][tid] = __uint_as_float((unsigned)vv);
    }
    const int pm2 = (tid < b * S2) ? tid : tid + S2;  // 496 pollers
    __syncthreads();

    int p = 0;
    for (int t = 0; t < C; ++t) {
      const float4* u4 = (const float4*)u[p];
      float4 ar = make_float4(0,0,0,0), az = make_float4(0,0,0,0),
             an = make_float4(0,0,0,0);
#pragma unroll
      for (int i = 0; i < 8; ++i) {
        const int c = (i + g) & 7;
        const float4 hv = u4[g * 8 + c];
        ar.x += wr[i].x*hv.x; ar.y += wr[i].y*hv.y; ar.z += wr[i].z*hv.z; ar.w += wr[i].w*hv.w;
        az.x += wz[i].x*hv.x; az.y += wz[i].y*hv.y; az.z += wz[i].z*hv.z; az.w += wz[i].w*hv.w;
        an.x += wn[i].x*hv.x; an.y += wn[i].y*hv.y; an.z += wn[i].z*hv.z; an.w += wn[i].w*hv.w;
      }
      float sr = (ar.x + ar.y) + (ar.z + ar.w);
      float sz = (az.x + az.y) + (az.z + az.w);
      float sn = (an.x + an.y) + (an.z + an.w);
      // r,z: full 32-lane sum. n: keep ih half (g<16) and hh half separate.
      sr += __shfl_xor(sr,1); sr += __shfl_xor(sr,2); sr += __shfl_xor(sr,4); sr += __shfl_xor(sr,8);
      sz += __shfl_xor(sz,1); sz += __shfl_xor(sz,2); sz += __shfl_xor(sz,4); sz += __shfl_xor(sz,8);
      sn += __shfl_xor(sn,1); sn += __shfl_xor(sn,2); sn += __shfl_xor(sn,4); sn += __shfl_xor(sn,8);
      sr += __shfl_xor(sr, 16);
      sz += __shfl_xor(sz, 16);
      const float snb = __shfl_xor(sn, 16);   // at g==0: hh-half sum

      const unsigned tag = t0 + (unsigned)t + 1u;
      if (g == 0) {
        const float r = sigf(sr + b1r);
        const float z = sigf(sz + b1z);
        const float n = tanhfast((sn + b1n) + r * (snb + bnj));
        const float hnew = n + z * (u[p][512 + jg] - n);
        h2c[(size_t)t * HDIM + jg] = hnew;
        __hip_atomic_store(&ring2[(size_t)((t & (RING2-1)) << 9) + jg],
            ((unsigned long long)tag << 32) | (unsigned)__float_as_uint(hnew),
            __ATOMIC_RELAXED, __HIP_MEMORY_SCOPE_AGENT);
        u[p ^ 1][512 + jg] = hnew;
      }

      // v8's combined poll: h1[t+1] -> u[p^1][tid]; peers' h2[t] ->
      // u[p^1][512+pm2]; both loads in flight in one retry loop.
      {
        bool n1 = (t + 1 < C);
        bool n2 = (tid < HDIM - S2);
        const size_t i1 = (size_t)(t + 1) * HDIM + tid;
        const size_t i2 = (size_t)((t & (RING2-1)) << 9) + pm2;
        while (n1 || n2) {
          unsigned long long v1 = 0, v2 = 0;
          if (n1) v1 = AL(&ring1[i1]);
          if (n2) v2 = AL(&ring2[i2]);
          if (n1 && (unsigned)(v1 >> 32) == tag + 1u) {
            u[p ^ 1][tid] = __uint_as_float((unsigned)v1);
            n1 = false;
          }
          if (n2 && (unsigned)(v2 >> 32) == tag) {
            u[p ^ 1][512 + pm2] = __uint_as_float((unsigned)v2);
            n2 = false;
          }
        }
      }
      __syncthreads();
      p ^= 1;
    }
  }
}

// ---------------------------------------------------------------------------
extern "C" void kernel_launch(void* const* d_in, const int* in_sizes, int n_in,
                              void* d_out, int out_size, void* d_ws, size_t ws_size,
                              hipStream_t stream) {
  const float* xs    = (const float*)d_in[0];
  const float* W_ih0 = (const float*)d_in[1];
  const float* W_hh0 = (const float*)d_in[2];
  const float* b0    = (const float*)d_in[3];
  const float* bn0   = (const float*)d_in[4];
  const float* W_ih1 = (const float*)d_in[5];
  const float* W_hh1 = (const float*)d_in[6];
  const float* b1    = (const float*)d_in[7];
  const float* bn1   = (const float*)d_in[8];
  const float* W_lin = (const float*)d_in[9];
  const float* b_lin = (const float*)d_in[10];
  float* out = (float*)d_out;

  // ws layout per chunk of C steps:
  //   ig0[C*1536] f32 | h2c[C*512] f32 | ring1[C*512] u64 | ring2[4*512] u64
  //   | h1carry[512] f32
  const size_t TAIL = (size_t)RING2 * HDIM * 8 + HDIM * 4;   // 18 KB
  int C = TSTEPS;
  while (C > 256 && (size_t)C * 12288 + TAIL > ws_size) C >>= 1;
  if ((size_t)C * 12288 + TAIL > ws_size) return;

  char* ws = (char*)d_ws;
  float*              igb = (float*)(ws);
  float*              h2c = (float*)(ws + (size_t)C * 6144);
  unsigned long long* r1  = (unsigned long long*)(ws + (size_t)C * 8192);
  unsigned long long* r2  = (unsigned long long*)(ws + (size_t)C * 12288);
  float*              h1c = (float*)(ws + (size_t)C * 12288 + RING2 * HDIM * 8);

  // Insurance: tags must start != any t0+t+1 (0xAA poison already can't match).
  hipMemsetAsync(r1, 0, (size_t)C * HDIM * 8 + RING2 * HDIM * 8, stream);

  const int nchunk = TSTEPS / C;
  for (int c = 0; c < nchunk; ++c) {
    const size_t t0 = (size_t)c * C;
    const int first = (c == 0);
    // igates0 = xs[t0:t0+C] @ W_ih0^T + b0     [C x 1536], K=128
    gemm_tn<128><<<dim3(C/128, G3/64), 256, 0, stream>>>(
        xs + t0 * 128, W_ih0, b0, igb, G3);
    // fused pipelined 2-layer scan chunk -> h2c
    gru2_scan<<<NB1 + NB2, 512, 0, stream>>>(
        igb, W_hh0, bn0, W_ih1, W_hh1, b1, bn1, h1c, h2c,
        r1, r2, C, (unsigned)t0, first);
    // out chunk = h2c @ W_lin^T + b_lin        [C x 128], K=512
    gemm_tn<512><<<dim3(C/128, 128/64), 256, 0, stream>>>(
        h2c, W_lin, b_lin, out + t0 * 128, 128);
  }
}